// Round 6
// baseline (5017.722 us; speedup 1.0000x reference)
//
#include <hip/hip_runtime.h>
#include <hip/hip_bf16.h>
#include <stdint.h>

// LSTM fused pipeline for B=256,S=512,D=256,H=256,O=128 on gfx950.
//
// Round-4 design (unchanged; rounds 4/5 were GPU-acquisition infra failures):
//  - k_lstm: 16 groups x 2 blocks (32 blocks x 512 thr, 8 waves). Wave owns 64
//    packed gate-cols (jpp = cb*512 + w*64 + gate*16 + hcl) -> weights 128 VGPR.
//    Gate sits in the MFMA N-frag index => each thread holds all 4 gates of one
//    (b,hc) pair in-register: ZERO shuffles in the gate phase.
//  - Cross-block sync: per-(grp,parity,block) flag on its OWN 128B line;
//    store-release own flag, acquire-poll sibling's (no RMW contention).
//  - Spin overlapped with next step's own-half-K MFMA (own h half is in LDS
//    before the barrier).
//  - xcat blobs laid out per-(lstm thread): 2 x uint4 per thread-step.

typedef unsigned short u16;
typedef unsigned int   u32;
typedef __bf16  bf16x8 __attribute__((ext_vector_type(8)));
typedef float   f32x4  __attribute__((ext_vector_type(4)));

union U4 { uint4 u; bf16x8 b; u16 s[8]; };

static __device__ __forceinline__ u16 f2b(float f){
  union { __hip_bfloat16 h; u16 u; } cv; cv.h = __float2bfloat16(f); return cv.u;
}
static __device__ __forceinline__ float b2f(u16 v){
  union { __hip_bfloat16 h; u16 u; } cv; cv.u = v; return __bfloat162float(cv.h);
}
static __device__ __forceinline__ float fsig(float x){
  return __builtin_amdgcn_rcpf(1.0f + __expf(-x));
}
static __device__ __forceinline__ float ftanh(float x){
  float ax = fabsf(x);
  float t  = __expf(-2.0f*ax);
  float r  = (1.0f - t) * __builtin_amdgcn_rcpf(1.0f + t);
  return copysignf(r, x);
}

struct PrepArgs {
  const float* wx[4]; const float* wh[4];
  const float* wxb[4]; const float* whb[4];
};

// ---------------------------------------------------------------- k_prep ----
// Row order jpp: gate=(jpp>>4)&3, hc=((jpp>>6)<<4)|(jpp&15).
// B-frag slot: lane l holds W[jb*16+(l&15)][kb*32+(l>>4)*8+e], slot=(jb*8+kb)*64+l.
__global__ void k_prep(PrepArgs P, u16* __restrict__ WxP, u16* __restrict__ WhP,
                       float* __restrict__ biasj)
{
  int sIdx = blockIdx.x*256 + threadIdx.x;          // 32768 frag slots
  int lane = sIdx & 63, kb = (sIdx>>6)&7, jb = sIdx>>9;
  int hcl = lane & 15;
  int gate = jb & 3, hc = ((jb>>2)<<4) | hcl;       // jpp = jb*16+hcl
  int kbase = kb*32 + ((lane>>4)<<3);
  const float* wx = P.wx[gate];
  const float* wh = P.wh[gate];
  U4 ox, oh;
  #pragma unroll
  for (int e=0; e<8; e++){
    ox.s[e] = f2b(wx[hc*256 + kbase + e]);
    oh.s[e] = f2b(wh[hc*256 + kbase + e]);
  }
  *(uint4*)(WxP + (size_t)sIdx*8) = ox.u;
  *(uint4*)(WhP + (size_t)sIdx*8) = oh.u;
  if (sIdx < 1024){                                  // biasj indexed by jpp
    int g2 = (sIdx>>4)&3, h2 = ((sIdx>>6)<<4)|(sIdx&15);
    biasj[sIdx] = P.wxb[g2][h2] + P.whb[g2][h2];
  }
}

// --------------------------------------------------------------- k_convx ----
__global__ void k_convx(const float* __restrict__ x, u16* __restrict__ xbf)
{
  int tid = blockIdx.x*256 + threadIdx.x;
  int ch = tid & 31;
  int b  = (tid>>5) & 255;
  int s  = tid >> 13;
  const float* src = x + ((size_t)b*512 + s)*256 + ch*8;
  float4 f0 = *(const float4*)(src);
  float4 f1 = *(const float4*)(src + 4);
  U4 o;
  o.s[0]=f2b(f0.x); o.s[1]=f2b(f0.y); o.s[2]=f2b(f0.z); o.s[3]=f2b(f0.w);
  o.s[4]=f2b(f1.x); o.s[5]=f2b(f1.y); o.s[6]=f2b(f1.z); o.s[7]=f2b(f1.w);
  u32 byteoff = (u32)(s*256 + b)*512u + (((u32)ch*16u) ^ ((u32)(b&7)<<4));
  *(uint4*)((char*)xbf + byteoff) = o.u;
}

// -------------------------------------------------------------- k_gemm_x ----
// Block: 128 batches (one s) x 256 jpp-cols (quarter jt), K=256, 8 waves.
// Epilogue writes xcat blobs: blob = s*32 + grp*2 + cb (cb=jt>>1), per lstm
// thread ltid: half0 (gates 0,1) at blob*8192+ltid*8, half1 at +4096.
__launch_bounds__(512)
__global__ void k_gemm_x(const u16* __restrict__ xbf, const u16* __restrict__ WxP,
                         const float* __restrict__ biasj,
                         const float* __restrict__ bgg, const float* __restrict__ bii,
                         const float* __restrict__ bff, const float* __restrict__ boo,
                         u16* __restrict__ xcat)
{
  __shared__ u16 smA[128*256];                       // 64 KB, swizzled
  int tid = threadIdx.x;
  int bid = blockIdx.x;                              // 4096
  int mt = bid >> 2, jt = bid & 3;
  int s = mt >> 1, b0 = (mt & 1)*128;

  const uint4* srcA = (const uint4*)(xbf + (size_t)(s*256 + b0)*256);
  uint4* dstA = (uint4*)smA;
  #pragma unroll
  for (int i=0; i<8; i++) dstA[tid + i*512] = srcA[tid + i*512];
  __syncthreads();

  int lane = tid & 63, wid = tid >> 6;
  int wm = wid >> 2, wn = wid & 3;
  int r16 = lane & 15, khi = lane >> 4;

  f32x4 acc[4][4] = {};
  #pragma unroll
  for (int kb=0; kb<8; kb++){
    bf16x8 a[4];
    #pragma unroll
    for (int mb=0; mb<4; mb++){
      int row = wm*64 + mb*16 + r16;
      u32 abyte = (u32)row*512u + ((u32)((kb*32 + khi*8)*2) ^ ((u32)(row&7)<<4));
      U4 t; t.u = *(const uint4*)((const char*)smA + abyte);
      a[mb] = t.b;
    }
    #pragma unroll
    for (int nb=0; nb<4; nb++){
      int jbg = jt*16 + wn*4 + nb;
      U4 t; t.u = *(const uint4*)(WxP + (size_t)((jbg*8 + kb)*64 + lane)*8);
      #pragma unroll
      for (int mb=0; mb<4; mb++)
        acc[mb][nb] = __builtin_amdgcn_mfma_f32_16x16x32_bf16(a[mb], t.b, acc[mb][nb], 0,0,0);
    }
  }

  // epilogue: jpp(nb) = jt*256 + wn*64 + nb*16 + r16
  // hc = (jt*4+wn)*16 + r16 (same for all nb); lstm w = (jt&1)*4+wn; cb = jt>>1
  int hc  = (jt*4 + wn)*16 + r16;
  int lw  = (jt&1)*4 + wn;
  int cbv = jt >> 1;
  int ltid = lw*64 + khi*16 + r16;
  const float* btab[4] = {bgg, bii, bff, boo};
  float bj[4];
  #pragma unroll
  for (int nb=0; nb<4; nb++) bj[nb] = biasj[jt*256 + wn*64 + nb*16 + r16];

  #pragma unroll
  for (int mb=0; mb<4; mb++){
    int grp = (b0>>4) + wm*4 + mb;
    U4 o1, o2;
    #pragma unroll
    for (int nb=0; nb<4; nb++){
      #pragma unroll
      for (int r=0; r<4; r++){
        int b = b0 + wm*64 + mb*16 + khi*4 + r;
        float v = acc[mb][nb][r] + bj[nb] + btab[nb][b*256 + hc];
        if (nb < 2) o1.s[nb*4 + r] = f2b(v);
        else        o2.s[(nb-2)*4 + r] = f2b(v);
      }
    }
    size_t base = (size_t)(s*32 + grp*2 + cbv)*8192 + (size_t)ltid*8;
    *(uint4*)(xcat + base)        = o1.u;
    *(uint4*)(xcat + base + 4096) = o2.u;
  }
}

// ---------------------------------------------------------------- k_lstm ----
// 32 blocks x 512 thr (8 waves). grp = (bid&7)*2 + ((bid>>3)&1), cb = bid>>4.
// Pair blocks (bids b, b+16) share bid&7 -> same XCD (perf heuristic).
// Wave w: jpp [cb*512+w*64, +64) -> wreg[4][8] (128 VGPR). Thread (w,khi,r16):
// hc = cb*128+w*16+r16, batches b = khi*4+r, all 4 gates in acc[nb].
__launch_bounds__(512, 2)
__global__ void k_lstm(const u16* __restrict__ xcat2, const u16* __restrict__ WhP,
                       u16* __restrict__ hx, int* __restrict__ flags,
                       float* __restrict__ hfin)
{
  __shared__ u16 hA[2][4096];                        // [par][b16][hc256] swz
  int tid = threadIdx.x, lane = tid & 63, w = tid >> 6;
  int bid = blockIdx.x;
  int grp = (bid & 7)*2 + ((bid >> 3) & 1);
  int cb  = bid >> 4;
  int r16 = lane & 15, khi = lane >> 4;
  int hc  = cb*128 + w*16 + r16;

  // weights -> VGPRs (once): jb16 = cb*32 + w*4 + nb
  bf16x8 wreg[4][8];
  #pragma unroll
  for (int nb=0; nb<4; nb++){
    int jb16 = cb*32 + w*4 + nb;
    #pragma unroll
    for (int kb=0; kb<8; kb++){
      U4 t; t.u = *(const uint4*)(WhP + (size_t)((jb16*8 + kb)*64 + lane)*8);
      wreg[nb][kb] = t.b;
    }
  }

  for (int i=tid; i<4096; i+=512) hA[0][i] = 0;      // h0 = 0 (both halves)
  __syncthreads();

  const u16* xbase = xcat2 + (size_t)(grp*2 + cb)*8192 + (size_t)tid*8;
  U4 xa, xb;
  xa.u = *(const uint4*)(xbase);
  xb.u = *(const uint4*)(xbase + 4096);

  float c[4] = {0.f,0.f,0.f,0.f};
  f32x4 acc[4] = {};                                 // own-half sums for step 0 (h0=0)
  int skb0 = (cb^1)*4, okb0 = cb*4;

  for (int t=0; t<511; t++){
    int par = t & 1;
    U4 xa_n, xb_n;                                   // prefetch step t+1
    {
      const u16* xn = xbase + (size_t)(t+1)*262144;
      xa_n.u = *(const uint4*)(xn);
      xb_n.u = *(const uint4*)(xn + 4096);
    }

    // sibling-half MFMA (h cols owned by the other block)
    #pragma unroll
    for (int k=0; k<4; k++){
      int kb = skb0 + k;
      u32 ab = (u32)r16*512u + (((u32)(kb*64 + khi*16)) ^ ((u32)(r16&7)<<4));
      U4 ta; ta.u = *(const uint4*)((const char*)hA[par] + ab);
      #pragma unroll
      for (int nb=0; nb<4; nb++)
        acc[nb] = __builtin_amdgcn_mfma_f32_16x16x32_bf16(ta.b, wreg[nb][kb], acc[nb], 0,0,0);
    }

    int pn = (t+1) & 1;
    u16* hxN = hx + (size_t)(pn*16 + grp)*4096;

    // gates: all 4 gates of (b,hc) in-thread; zero shuffles
    #pragma unroll
    for (int r=0; r<4; r++){
      float gv = ftanh(acc[0][r] + b2f(xa.s[0+r]));
      float iv = fsig (acc[1][r] + b2f(xa.s[4+r]));
      float fv = fsig (acc[2][r] + b2f(xb.s[0+r]));
      float ov = fsig (acc[3][r] + b2f(xb.s[4+r]));
      float cn = gv*iv + c[r]*fv;
      c[r] = cn;
      float hv = ftanh(cn)*ov;
      int b = khi*4 + r;
      u16 hb16 = f2b(hv);
      *(u16*)((char*)hA[par^1] +
              ((u32)b*512u + (((u32)hc*2u) ^ ((u32)(b&7)<<4)))) = hb16;
      hxN[b*256 + hc] = hb16;
    }

    __syncthreads();                                  // all stores drained (vmcnt0)

    int val = (t>>1) + 1;
    if (tid == 0)
      __hip_atomic_store(&flags[((grp*2 + pn)*2 + cb)*32], val,
                         __ATOMIC_RELEASE, __HIP_MEMORY_SCOPE_AGENT);

    // own-half MFMA for step t+1 (own h already in hA[par^1]) — overlaps spin
    #pragma unroll
    for (int nb=0; nb<4; nb++) acc[nb] = (f32x4){0.f,0.f,0.f,0.f};
    #pragma unroll
    for (int k=0; k<4; k++){
      int kb = okb0 + k;
      u32 ab = (u32)r16*512u + (((u32)(kb*64 + khi*16)) ^ ((u32)(r16&7)<<4));
      U4 ta; ta.u = *(const uint4*)((const char*)hA[par^1] + ab);
      #pragma unroll
      for (int nb=0; nb<4; nb++)
        acc[nb] = __builtin_amdgcn_mfma_f32_16x16x32_bf16(ta.b, wreg[nb][kb], acc[nb], 0,0,0);
    }

    if (tid == 0){
      const int* sf = &flags[((grp*2 + pn)*2 + (cb^1))*32];
      while (__hip_atomic_load(sf, __ATOMIC_ACQUIRE, __HIP_MEMORY_SCOPE_AGENT) < val)
        __builtin_amdgcn_s_sleep(1);
    }
    __syncthreads();

    // fill sibling half of hA[par^1] from hx
    if (tid < 256){
      int b = tid >> 4, hcc = (tid & 15)*8;
      int hcs = (cb^1)*128 + hcc;
      U4 tv; tv.u = *(const uint4*)(hxN + b*256 + hcs);
      *(uint4*)((char*)hA[par^1] +
                ((u32)b*512u + (((u32)(hcs*2)) ^ ((u32)(b&7)<<4)))) = tv.u;
    }
    __syncthreads();
    xa = xa_n; xb = xb_n;
  }

  // epilogue t = 511: h_511 is in hA[1]; acc holds own-half sums
  {
    int par = 1;
    #pragma unroll
    for (int k=0; k<4; k++){
      int kb = skb0 + k;
      u32 ab = (u32)r16*512u + (((u32)(kb*64 + khi*16)) ^ ((u32)(r16&7)<<4));
      U4 ta; ta.u = *(const uint4*)((const char*)hA[par] + ab);
      #pragma unroll
      for (int nb=0; nb<4; nb++)
        acc[nb] = __builtin_amdgcn_mfma_f32_16x16x32_bf16(ta.b, wreg[nb][kb], acc[nb], 0,0,0);
    }
    #pragma unroll
    for (int r=0; r<4; r++){
      float gv = ftanh(acc[0][r] + b2f(xa.s[0+r]));
      float iv = fsig (acc[1][r] + b2f(xa.s[4+r]));
      float fv = fsig (acc[2][r] + b2f(xb.s[0+r]));
      float ov = fsig (acc[3][r] + b2f(xb.s[4+r]));
      float cn = gv*iv + c[r]*fv;
      float hv = ftanh(cn)*ov;
      int b = khi*4 + r;
      hfin[(grp*16 + b)*256 + hc] = hv;
    }
  }
}

// ---------------------------------------------------------------- k_proj ----
__global__ void k_proj(const float* __restrict__ hfin, const float* __restrict__ Wph_w,
                       const float* __restrict__ Wph_b, const float* __restrict__ bp,
                       float* __restrict__ out)
{
  __shared__ float hrow[256];
  __shared__ float pbuf[128];
  int b = blockIdx.x, tid = threadIdx.x;             // 128 threads
  hrow[tid]       = hfin[b*256 + tid];
  hrow[tid + 128] = hfin[b*256 + 128 + tid];
  __syncthreads();
  const float* wr = Wph_w + (size_t)tid*256;
  float acc = Wph_b[tid] + bp[b*128 + tid];
  #pragma unroll 8
  for (int k=0; k<256; k++) acc += hrow[k]*wr[k];
  pbuf[tid] = acc;
  __syncthreads();
  float mx = -1e30f;
  for (int i=0; i<128; i++) mx = fmaxf(mx, pbuf[i]);
  float e = __expf(acc - mx);
  __syncthreads();
  pbuf[tid] = e;
  __syncthreads();
  float sum = 0.f;
  for (int i=0; i<128; i++) sum += pbuf[i];
  out[b*128 + tid] = e / sum;
}

// ----------------------------------------------------------------- launch ----
extern "C" void kernel_launch(void* const* d_in, const int* in_sizes, int n_in,
                              void* d_out, int out_size, void* d_ws, size_t ws_size,
                              hipStream_t stream)
{
  (void)in_sizes; (void)n_in; (void)out_size; (void)ws_size;
  const float* x     = (const float*)d_in[0];
  const float* Wph_w = (const float*)d_in[17];
  const float* Wph_b = (const float*)d_in[18];
  const float* bg    = (const float*)d_in[19];
  const float* bi    = (const float*)d_in[20];
  const float* bf    = (const float*)d_in[21];
  const float* bo    = (const float*)d_in[22];
  const float* bp    = (const float*)d_in[23];

  PrepArgs P;
  for (int g=0; g<4; g++){
    P.wx[g]  = (const float*)d_in[1 + 4*g];
    P.wxb[g] = (const float*)d_in[2 + 4*g];
    P.wh[g]  = (const float*)d_in[3 + 4*g];
    P.whb[g] = (const float*)d_in[4 + 4*g];
  }

  char* ws = (char*)d_ws;
  u16*   xcat  = (u16*)(ws);                                   // 268435456 B
  u16*   xbf   = (u16*)(ws + 268435456);                       //  67108864 B (dead after k_gemm_x)
  u16*   hx    = (u16*)(ws + 268435456);                       //    262144 B (reuses xbf)
  int*   flags = (int*)(ws + 268435456 + 262144);              //      8192 B
  u16*   WxP   = (u16*)(ws + 268435456 + 67108864);            //    524288 B
  u16*   WhP   = (u16*)(ws + 268435456 + 67108864 + 524288);   //    524288 B
  float* biasj = (float*)(ws + 268435456 + 67108864 + 1048576);//      4096 B
  float* hfin  = (float*)(ws + 268435456 + 67108864 + 1048576 + 4096); // 262144 B

  k_prep <<<128,   256, 0, stream>>>(P, WxP, WhP, biasj);
  k_convx<<<16384, 256, 0, stream>>>(x, xbf);
  k_gemm_x<<<4096, 512, 0, stream>>>(xbf, WxP, biasj, bg, bi, bf, bo, xcat);
  hipMemsetAsync(flags, 0, 8192, stream);
  k_lstm <<<32,    512, 0, stream>>>(xcat, WhP, hx, flags, hfin);
  k_proj <<<256,   128, 0, stream>>>(hfin, Wph_w, Wph_b, bp, (float*)d_out);
}

// Round 7
// 4970.193 us; speedup vs baseline: 1.0096x; 1.0096x over previous
//
#include <hip/hip_runtime.h>
#include <hip/hip_bf16.h>
#include <stdint.h>

// LSTM fused pipeline for B=256,S=512,D=256,H=256,O=128 on gfx950.
//
// Round-7 change (only k_lstm): cross-block h exchange via RELAXED agent-scope
// cache-bypassing atomics (per-op scope bits, NO buffer_wbl2/buffer_inv fence
// storm — that was ~9us/step in R3/R6). Ordering: __syncthreads drains
// vmcnt(0) per wave => bypass stores globally visible before the (relaxed)
// flag store that follows the barrier. h repacked through LDS: exactly one
// u64 bypass store + one u64 bypass load per thread per step.
//
// Structure (unchanged from R4/R6):
//  - 16 groups x 2 blocks (32 blocks x 512 thr, 8 waves). Wave owns 64 packed
//    gate-cols (jpp = cb*512 + w*64 + gate*16 + hcl) -> weights 128 VGPR.
//  - Gate in MFMA N-frag index => all 4 gates of one (b,hc) in-thread, zero
//    shuffles.
//  - Spin overlapped with next step's own-half-K MFMA.
//  - xcat blobs laid out per-(lstm thread): 2 x uint4 per thread-step.

typedef unsigned short u16;
typedef unsigned int   u32;
typedef unsigned long long u64;
typedef __bf16  bf16x8 __attribute__((ext_vector_type(8)));
typedef float   f32x4  __attribute__((ext_vector_type(4)));

union U4 { uint4 u; bf16x8 b; u16 s[8]; };

static __device__ __forceinline__ u16 f2b(float f){
  union { __hip_bfloat16 h; u16 u; } cv; cv.h = __float2bfloat16(f); return cv.u;
}
static __device__ __forceinline__ float b2f(u16 v){
  union { __hip_bfloat16 h; u16 u; } cv; cv.u = v; return __bfloat162float(cv.h);
}
static __device__ __forceinline__ float fsig(float x){
  return __builtin_amdgcn_rcpf(1.0f + __expf(-x));
}
static __device__ __forceinline__ float ftanh(float x){
  float ax = fabsf(x);
  float t  = __expf(-2.0f*ax);
  float r  = (1.0f - t) * __builtin_amdgcn_rcpf(1.0f + t);
  return copysignf(r, x);
}

struct PrepArgs {
  const float* wx[4]; const float* wh[4];
  const float* wxb[4]; const float* whb[4];
};

// ---------------------------------------------------------------- k_prep ----
// Row order jpp: gate=(jpp>>4)&3, hc=((jpp>>6)<<4)|(jpp&15).
// B-frag slot: lane l holds W[jb*16+(l&15)][kb*32+(l>>4)*8+e], slot=(jb*8+kb)*64+l.
__global__ void k_prep(PrepArgs P, u16* __restrict__ WxP, u16* __restrict__ WhP,
                       float* __restrict__ biasj)
{
  int sIdx = blockIdx.x*256 + threadIdx.x;          // 32768 frag slots
  int lane = sIdx & 63, kb = (sIdx>>6)&7, jb = sIdx>>9;
  int hcl = lane & 15;
  int gate = jb & 3, hc = ((jb>>2)<<4) | hcl;       // jpp = jb*16+hcl
  int kbase = kb*32 + ((lane>>4)<<3);
  const float* wx = P.wx[gate];
  const float* wh = P.wh[gate];
  U4 ox, oh;
  #pragma unroll
  for (int e=0; e<8; e++){
    ox.s[e] = f2b(wx[hc*256 + kbase + e]);
    oh.s[e] = f2b(wh[hc*256 + kbase + e]);
  }
  *(uint4*)(WxP + (size_t)sIdx*8) = ox.u;
  *(uint4*)(WhP + (size_t)sIdx*8) = oh.u;
  if (sIdx < 1024){                                  // biasj indexed by jpp
    int g2 = (sIdx>>4)&3, h2 = ((sIdx>>6)<<4)|(sIdx&15);
    biasj[sIdx] = P.wxb[g2][h2] + P.whb[g2][h2];
  }
}

// --------------------------------------------------------------- k_convx ----
__global__ void k_convx(const float* __restrict__ x, u16* __restrict__ xbf)
{
  int tid = blockIdx.x*256 + threadIdx.x;
  int ch = tid & 31;
  int b  = (tid>>5) & 255;
  int s  = tid >> 13;
  const float* src = x + ((size_t)b*512 + s)*256 + ch*8;
  float4 f0 = *(const float4*)(src);
  float4 f1 = *(const float4*)(src + 4);
  U4 o;
  o.s[0]=f2b(f0.x); o.s[1]=f2b(f0.y); o.s[2]=f2b(f0.z); o.s[3]=f2b(f0.w);
  o.s[4]=f2b(f1.x); o.s[5]=f2b(f1.y); o.s[6]=f2b(f1.z); o.s[7]=f2b(f1.w);
  u32 byteoff = (u32)(s*256 + b)*512u + (((u32)ch*16u) ^ ((u32)(b&7)<<4));
  *(uint4*)((char*)xbf + byteoff) = o.u;
}

// -------------------------------------------------------------- k_gemm_x ----
// Block: 128 batches (one s) x 256 jpp-cols (quarter jt), K=256, 8 waves.
// Epilogue writes xcat blobs: blob = s*32 + grp*2 + cb (cb=jt>>1), per lstm
// thread ltid: half0 (gates 0,1) at blob*8192+ltid*8, half1 at +4096.
__launch_bounds__(512)
__global__ void k_gemm_x(const u16* __restrict__ xbf, const u16* __restrict__ WxP,
                         const float* __restrict__ biasj,
                         const float* __restrict__ bgg, const float* __restrict__ bii,
                         const float* __restrict__ bff, const float* __restrict__ boo,
                         u16* __restrict__ xcat)
{
  __shared__ u16 smA[128*256];                       // 64 KB, swizzled
  int tid = threadIdx.x;
  int bid = blockIdx.x;                              // 4096
  int mt = bid >> 2, jt = bid & 3;
  int s = mt >> 1, b0 = (mt & 1)*128;

  const uint4* srcA = (const uint4*)(xbf + (size_t)(s*256 + b0)*256);
  uint4* dstA = (uint4*)smA;
  #pragma unroll
  for (int i=0; i<8; i++) dstA[tid + i*512] = srcA[tid + i*512];
  __syncthreads();

  int lane = tid & 63, wid = tid >> 6;
  int wm = wid >> 2, wn = wid & 3;
  int r16 = lane & 15, khi = lane >> 4;

  f32x4 acc[4][4] = {};
  #pragma unroll
  for (int kb=0; kb<8; kb++){
    bf16x8 a[4];
    #pragma unroll
    for (int mb=0; mb<4; mb++){
      int row = wm*64 + mb*16 + r16;
      u32 abyte = (u32)row*512u + ((u32)((kb*32 + khi*8)*2) ^ ((u32)(row&7)<<4));
      U4 t; t.u = *(const uint4*)((const char*)smA + abyte);
      a[mb] = t.b;
    }
    #pragma unroll
    for (int nb=0; nb<4; nb++){
      int jbg = jt*16 + wn*4 + nb;
      U4 t; t.u = *(const uint4*)(WxP + (size_t)((jbg*8 + kb)*64 + lane)*8);
      #pragma unroll
      for (int mb=0; mb<4; mb++)
        acc[mb][nb] = __builtin_amdgcn_mfma_f32_16x16x32_bf16(a[mb], t.b, acc[mb][nb], 0,0,0);
    }
  }

  // epilogue: jpp(nb) = jt*256 + wn*64 + nb*16 + r16
  // hc = (jt*4+wn)*16 + r16 (same for all nb); lstm w = (jt&1)*4+wn; cb = jt>>1
  int hc  = (jt*4 + wn)*16 + r16;
  int lw  = (jt&1)*4 + wn;
  int cbv = jt >> 1;
  int ltid = lw*64 + khi*16 + r16;
  const float* btab[4] = {bgg, bii, bff, boo};
  float bj[4];
  #pragma unroll
  for (int nb=0; nb<4; nb++) bj[nb] = biasj[jt*256 + wn*64 + nb*16 + r16];

  #pragma unroll
  for (int mb=0; mb<4; mb++){
    int grp = (b0>>4) + wm*4 + mb;
    U4 o1, o2;
    #pragma unroll
    for (int nb=0; nb<4; nb++){
      #pragma unroll
      for (int r=0; r<4; r++){
        int b = b0 + wm*64 + mb*16 + khi*4 + r;
        float v = acc[mb][nb][r] + bj[nb] + btab[nb][b*256 + hc];
        if (nb < 2) o1.s[nb*4 + r] = f2b(v);
        else        o2.s[(nb-2)*4 + r] = f2b(v);
      }
    }
    size_t base = (size_t)(s*32 + grp*2 + cbv)*8192 + (size_t)ltid*8;
    *(uint4*)(xcat + base)        = o1.u;
    *(uint4*)(xcat + base + 4096) = o2.u;
  }
}

// ---------------------------------------------------------------- k_lstm ----
// 32 blocks x 512 thr (8 waves). grp = (bid&7)*2 + ((bid>>3)&1), cb = bid>>4.
// Wave w: jpp [cb*512+w*64, +64) -> wreg[4][8] (128 VGPR). Thread (w,khi,r16):
// hc = cb*128+w*16+r16, batches b = khi*4+r, all 4 gates in acc[nb].
// Exchange: repack own h half via LDS -> 1 u64 relaxed-AGENT atomic store per
// thread; fill sibling half via 1 u64 relaxed-AGENT atomic load per thread.
// No release/acquire => no L2 writeback/invalidate fences.
__launch_bounds__(512, 2)
__global__ void k_lstm(const u16* __restrict__ xcat2, const u16* __restrict__ WhP,
                       u16* __restrict__ hx, int* __restrict__ flags,
                       float* __restrict__ hfin)
{
  __shared__ u16 hA[2][4096];                        // [par][b16][hc256] swz
  int tid = threadIdx.x, lane = tid & 63, w = tid >> 6;
  int bid = blockIdx.x;
  int grp = (bid & 7)*2 + ((bid >> 3) & 1);
  int cb  = bid >> 4;
  int r16 = lane & 15, khi = lane >> 4;
  int hc  = cb*128 + w*16 + r16;

  // weights -> VGPRs (once): jb16 = cb*32 + w*4 + nb
  bf16x8 wreg[4][8];
  #pragma unroll
  for (int nb=0; nb<4; nb++){
    int jb16 = cb*32 + w*4 + nb;
    #pragma unroll
    for (int kb=0; kb<8; kb++){
      U4 t; t.u = *(const uint4*)(WhP + (size_t)((jb16*8 + kb)*64 + lane)*8);
      wreg[nb][kb] = t.b;
    }
  }

  for (int i=tid; i<4096; i+=512) hA[0][i] = 0;      // h0 = 0
  __syncthreads();

  const u16* xbase = xcat2 + (size_t)(grp*2 + cb)*8192 + (size_t)tid*8;
  U4 xa, xb;
  xa.u = *(const uint4*)(xbase);
  xb.u = *(const uint4*)(xbase + 4096);

  // exchange thread mapping: eb = batch row, ehq = u64 quad (4 hc) in half
  int eb = tid >> 5, ehq = tid & 31;
  u32 exLds = ((u32)eb*512u + (u32)(cb*256 + ehq*8)) ^ ((u32)(eb&7)<<4);
  u32 exHx  = (u32)(eb*256 + cb*128 + ehq*4);        // u16 index
  u32 flLds = ((u32)eb*512u + (u32)((cb^1)*256 + ehq*8)) ^ ((u32)(eb&7)<<4);
  u32 flHx  = (u32)(eb*256 + (cb^1)*128 + ehq*4);

  float c[4] = {0.f,0.f,0.f,0.f};
  f32x4 acc[4] = {};                                 // own-half sums for step 0 (h0=0)
  int skb0 = (cb^1)*4, okb0 = cb*4;

  for (int t=0; t<511; t++){
    int par = t & 1;
    U4 xa_n, xb_n;                                   // prefetch step t+1
    {
      const u16* xn = xbase + (size_t)(t+1)*262144;
      xa_n.u = *(const uint4*)(xn);
      xb_n.u = *(const uint4*)(xn + 4096);
    }

    // sibling-half MFMA (h cols owned by the other block)
    #pragma unroll
    for (int k=0; k<4; k++){
      int kb = skb0 + k;
      u32 ab = (u32)r16*512u + (((u32)(kb*64 + khi*16)) ^ ((u32)(r16&7)<<4));
      U4 ta; ta.u = *(const uint4*)((const char*)hA[par] + ab);
      #pragma unroll
      for (int nb=0; nb<4; nb++)
        acc[nb] = __builtin_amdgcn_mfma_f32_16x16x32_bf16(ta.b, wreg[nb][kb], acc[nb], 0,0,0);
    }

    int pn = (t+1) & 1;
    u16* hxN = hx + (size_t)(pn*16 + grp)*4096;

    // gates: all 4 gates of (b,hc) in-thread; LDS stores only
    #pragma unroll
    for (int r=0; r<4; r++){
      float gv = ftanh(acc[0][r] + b2f(xa.s[0+r]));
      float iv = fsig (acc[1][r] + b2f(xa.s[4+r]));
      float fv = fsig (acc[2][r] + b2f(xb.s[0+r]));
      float ov = fsig (acc[3][r] + b2f(xb.s[4+r]));
      float cn = gv*iv + c[r]*fv;
      c[r] = cn;
      float hv = ftanh(cn)*ov;
      int b = khi*4 + r;
      *(u16*)((char*)hA[par^1] +
              ((u32)b*512u + (((u32)hc*2u) ^ ((u32)(b&7)<<4)))) = f2b(hv);
    }

    __syncthreads();                                  // own half complete in LDS

    // export own half: 1 u64 bypass store per thread
    u64 hv64 = *(const u64*)((const char*)hA[par^1] + exLds);
    __hip_atomic_store((u64*)(hxN + exHx), hv64,
                       __ATOMIC_RELAXED, __HIP_MEMORY_SCOPE_AGENT);

    __syncthreads();                                  // vmcnt(0)/wave => exports visible

    int val = (t>>1) + 1;
    if (tid == 0)
      __hip_atomic_store(&flags[((grp*2 + pn)*2 + cb)*32], val,
                         __ATOMIC_RELAXED, __HIP_MEMORY_SCOPE_AGENT);

    // own-half MFMA for step t+1 (own h already in hA[par^1]) — overlaps RTT
    #pragma unroll
    for (int nb=0; nb<4; nb++) acc[nb] = (f32x4){0.f,0.f,0.f,0.f};
    #pragma unroll
    for (int k=0; k<4; k++){
      int kb = okb0 + k;
      u32 ab = (u32)r16*512u + (((u32)(kb*64 + khi*16)) ^ ((u32)(r16&7)<<4));
      U4 ta; ta.u = *(const uint4*)((const char*)hA[par^1] + ab);
      #pragma unroll
      for (int nb=0; nb<4; nb++)
        acc[nb] = __builtin_amdgcn_mfma_f32_16x16x32_bf16(ta.b, wreg[nb][kb], acc[nb], 0,0,0);
    }

    if (tid == 0){
      const int* sf = &flags[((grp*2 + pn)*2 + (cb^1))*32];
      while (__hip_atomic_load(sf, __ATOMIC_RELAXED, __HIP_MEMORY_SCOPE_AGENT) < val)
        __builtin_amdgcn_s_sleep(1);
    }
    __syncthreads();

    // fill sibling half: 1 u64 bypass load per thread
    u64 sv = __hip_atomic_load((const u64*)(hxN + flHx),
                               __ATOMIC_RELAXED, __HIP_MEMORY_SCOPE_AGENT);
    *(u64*)((char*)hA[par^1] + flLds) = sv;
    __syncthreads();
    xa = xa_n; xb = xb_n;
  }

  // epilogue t = 511: h_511 is in hA[1]; acc holds own-half sums
  {
    int par = 1;
    #pragma unroll
    for (int k=0; k<4; k++){
      int kb = skb0 + k;
      u32 ab = (u32)r16*512u + (((u32)(kb*64 + khi*16)) ^ ((u32)(r16&7)<<4));
      U4 ta; ta.u = *(const uint4*)((const char*)hA[par] + ab);
      #pragma unroll
      for (int nb=0; nb<4; nb++)
        acc[nb] = __builtin_amdgcn_mfma_f32_16x16x32_bf16(ta.b, wreg[nb][kb], acc[nb], 0,0,0);
    }
    #pragma unroll
    for (int r=0; r<4; r++){
      float gv = ftanh(acc[0][r] + b2f(xa.s[0+r]));
      float iv = fsig (acc[1][r] + b2f(xa.s[4+r]));
      float fv = fsig (acc[2][r] + b2f(xb.s[0+r]));
      float ov = fsig (acc[3][r] + b2f(xb.s[4+r]));
      float cn = gv*iv + c[r]*fv;
      float hv = ftanh(cn)*ov;
      int b = khi*4 + r;
      hfin[(grp*16 + b)*256 + hc] = hv;
    }
  }
}

// ---------------------------------------------------------------- k_proj ----
__global__ void k_proj(const float* __restrict__ hfin, const float* __restrict__ Wph_w,
                       const float* __restrict__ Wph_b, const float* __restrict__ bp,
                       float* __restrict__ out)
{
  __shared__ float hrow[256];
  __shared__ float pbuf[128];
  int b = blockIdx.x, tid = threadIdx.x;             // 128 threads
  hrow[tid]       = hfin[b*256 + tid];
  hrow[tid + 128] = hfin[b*256 + 128 + tid];
  __syncthreads();
  const float* wr = Wph_w + (size_t)tid*256;
  float acc = Wph_b[tid] + bp[b*128 + tid];
  #pragma unroll 8
  for (int k=0; k<256; k++) acc += hrow[k]*wr[k];
  pbuf[tid] = acc;
  __syncthreads();
  float mx = -1e30f;
  for (int i=0; i<128; i++) mx = fmaxf(mx, pbuf[i]);
  float e = __expf(acc - mx);
  __syncthreads();
  pbuf[tid] = e;
  __syncthreads();
  float sum = 0.f;
  for (int i=0; i<128; i++) sum += pbuf[i];
  out[b*128 + tid] = e / sum;
}

// ----------------------------------------------------------------- launch ----
extern "C" void kernel_launch(void* const* d_in, const int* in_sizes, int n_in,
                              void* d_out, int out_size, void* d_ws, size_t ws_size,
                              hipStream_t stream)
{
  (void)in_sizes; (void)n_in; (void)out_size; (void)ws_size;
  const float* x     = (const float*)d_in[0];
  const float* Wph_w = (const float*)d_in[17];
  const float* Wph_b = (const float*)d_in[18];
  const float* bg    = (const float*)d_in[19];
  const float* bi    = (const float*)d_in[20];
  const float* bf    = (const float*)d_in[21];
  const float* bo    = (const float*)d_in[22];
  const float* bp    = (const float*)d_in[23];

  PrepArgs P;
  for (int g=0; g<4; g++){
    P.wx[g]  = (const float*)d_in[1 + 4*g];
    P.wxb[g] = (const float*)d_in[2 + 4*g];
    P.wh[g]  = (const float*)d_in[3 + 4*g];
    P.whb[g] = (const float*)d_in[4 + 4*g];
  }

  char* ws = (char*)d_ws;
  u16*   xcat  = (u16*)(ws);                                   // 268435456 B
  u16*   xbf   = (u16*)(ws + 268435456);                       //  67108864 B (dead after k_gemm_x)
  u16*   hx    = (u16*)(ws + 268435456);                       //    262144 B (reuses xbf)
  int*   flags = (int*)(ws + 268435456 + 262144);              //      8192 B
  u16*   WxP   = (u16*)(ws + 268435456 + 67108864);            //    524288 B
  u16*   WhP   = (u16*)(ws + 268435456 + 67108864 + 524288);   //    524288 B
  float* biasj = (float*)(ws + 268435456 + 67108864 + 1048576);//      4096 B
  float* hfin  = (float*)(ws + 268435456 + 67108864 + 1048576 + 4096); // 262144 B

  k_prep <<<128,   256, 0, stream>>>(P, WxP, WhP, biasj);
  k_convx<<<16384, 256, 0, stream>>>(x, xbf);
  k_gemm_x<<<4096, 512, 0, stream>>>(xbf, WxP, biasj, bg, bi, bf, bo, xcat);
  hipMemsetAsync(flags, 0, 8192, stream);
  k_lstm <<<32,    512, 0, stream>>>(xcat, WhP, hx, flags, hfin);
  k_proj <<<256,   128, 0, stream>>>(hfin, Wph_w, Wph_b, bp, (float*)d_out);
}